// Round 1
// baseline (127.766 us; speedup 1.0000x reference)
//
#include <hip/hip_runtime.h>
#include <math.h>

#define N 512
#define D 512
#define NC 10
#define EPSF 1e-8f

// ---------------- Kernel 1: row-normalize + class_pos ----------------
__global__ __launch_bounds__(256) void k_normalize(
    const float* __restrict__ pred,
    const float* __restrict__ dist_raw,
    float* __restrict__ xn,
    float* __restrict__ class_pos) {
  int i = blockIdx.x;
  int tid = threadIdx.x;  // 256 threads, D=512 -> 2 elems/thread
  const float* row = pred + (size_t)i * D;
  float v0 = row[tid];
  float v1 = row[tid + 256];
  float ss = v0 * v0 + v1 * v1;
  // wave (64-lane) reduce
  for (int off = 32; off > 0; off >>= 1) ss += __shfl_down(ss, off);
  __shared__ float s_part[4];
  int lane = tid & 63, wv = tid >> 6;
  if (lane == 0) s_part[wv] = ss;
  __syncthreads();
  __shared__ float s_inv;
  if (tid == 0) {
    float tot = s_part[0] + s_part[1] + s_part[2] + s_part[3];
    float norm = sqrtf(tot);
    s_inv = 1.0f / fmaxf(norm, EPSF);
  }
  __syncthreads();
  float inv = s_inv;
  xn[(size_t)i * D + tid] = v0 * inv;
  xn[(size_t)i * D + tid + 256] = v1 * inv;

  // class_pos = [0, cumsum(softplus(dist_raw))]  (9 values -> 10 entries)
  if (i == 0 && tid == 0) {
    float acc = 0.0f;
    class_pos[0] = 0.0f;
    for (int c = 0; c < NC - 1; c++) {
      acc += log1pf(expf(dist_raw[c]));
      class_pos[c + 1] = acc;
    }
  }
}

// ---------------- Kernel 2: per-row loss ----------------
__global__ __launch_bounds__(256) void k_rows(
    const float* __restrict__ xn,
    const int* __restrict__ target,
    const float* __restrict__ class_pos,
    float* __restrict__ tot) {
  int i = blockIdx.x;
  int tid = threadIdx.x;

  __shared__ float s_xi[D];     // this row's normalized vector
  __shared__ float s_cos[N];    // cos[i][j]
  __shared__ float s_a[N];      // compacted: cos+margin over negatives
  __shared__ float s_p[N];      // compacted: cos over positives
  __shared__ float s_cp[NC];
  __shared__ int s_np, s_nn, s_ti;

  if (tid == 0) { s_np = 0; s_nn = 0; s_ti = target[i]; }
  if (tid < NC) s_cp[tid] = class_pos[tid];
  s_xi[tid] = xn[(size_t)i * D + tid];
  s_xi[tid + 256] = xn[(size_t)i * D + tid + 256];
  __syncthreads();
  int ti = s_ti;

  // cos row: each thread does 2 dot products of length 512
  for (int j = tid; j < N; j += 256) {
    const float* xj = xn + (size_t)j * D;
    float acc = 0.0f;
    for (int d = 0; d < D; d += 4) {
      float4 a = *(const float4*)(s_xi + d);       // broadcast LDS read
      float4 b = *(const float4*)(xj + d);
      acc += a.x * b.x + a.y * b.y + a.z * b.z + a.w * b.w;
    }
    s_cos[j] = acc;
  }
  __syncthreads();

  // compact positives / negatives
  for (int j = tid; j < N; j += 256) {
    int tj = target[j];
    if (tj != ti) {
      float m = fabsf(s_cp[ti] - s_cp[tj]);
      int idx = atomicAdd(&s_nn, 1);
      s_a[idx] = s_cos[j] + m;
    } else if (j != i) {
      int idx = atomicAdd(&s_np, 1);
      s_p[idx] = s_cos[j];
    }
  }
  __syncthreads();

  int np = s_np, nn = s_nn;
  float acc = 0.0f;
  for (int kk = 0; kk < np; kk++) {
    float ck = s_p[kk];
    for (int jj = tid; jj < nn; jj += 256) {
      float d = s_a[jj] - ck;
      acc += (d > 0.0f) ? d : 0.0f;
    }
  }
  // block reduce
  for (int off = 32; off > 0; off >>= 1) acc += __shfl_down(acc, off);
  __shared__ float s_part[4];
  int lane = tid & 63, wv = tid >> 6;
  if (lane == 0) s_part[wv] = acc;
  __syncthreads();
  if (tid == 0) {
    float total = s_part[0] + s_part[1] + s_part[2] + s_part[3];
    float r = 0.0f;
    if (np > 0 && nn > 0)
      r = total / ((float)nn * (float)nn * (float)np);
    tot[i] = r;
  }
}

// ---------------- Kernel 3: mean ----------------
__global__ __launch_bounds__(256) void k_reduce(
    const float* __restrict__ tot, float* __restrict__ out) {
  int tid = threadIdx.x;
  float v = tot[tid] + tot[tid + 256];
  for (int off = 32; off > 0; off >>= 1) v += __shfl_down(v, off);
  __shared__ float s_part[4];
  if ((tid & 63) == 0) s_part[tid >> 6] = v;
  __syncthreads();
  if (tid == 0)
    out[0] = (s_part[0] + s_part[1] + s_part[2] + s_part[3]) / (float)N;
}

extern "C" void kernel_launch(void* const* d_in, const int* in_sizes, int n_in,
                              void* d_out, int out_size, void* d_ws, size_t ws_size,
                              hipStream_t stream) {
  const float* pred = (const float*)d_in[0];
  const float* dist_raw = (const float*)d_in[1];
  const int* target = (const int*)d_in[2];
  float* out = (float*)d_out;

  float* xn = (float*)d_ws;                 // N*D floats = 1 MB
  float* class_pos = xn + (size_t)N * D;    // 16 floats (10 used)
  float* tot = class_pos + 16;              // N floats

  k_normalize<<<N, 256, 0, stream>>>(pred, dist_raw, xn, class_pos);
  k_rows<<<N, 256, 0, stream>>>(xn, target, class_pos, tot);
  k_reduce<<<1, 256, 0, stream>>>(tot, out);
}

// Round 2
// 81.671 us; speedup vs baseline: 1.5644x; 1.5644x over previous
//
#include <hip/hip_runtime.h>
#include <math.h>

#define N 512
#define D 512
#define NC 10
#define EPSF 1e-8f

// ---------------- Kernel 1: Gram GEMM  G = pred @ pred^T ----------------
// grid (16,16), block 256. 32x32 output tile, BK=32, 2x2 register tile.
// Diagonal blocks also emit inv_n; block (0,0) emits class_pos and zeroes out.
__global__ __launch_bounds__(256) void k_gram(
    const float* __restrict__ pred,
    const float* __restrict__ dist_raw,
    float* __restrict__ G,
    float* __restrict__ inv_n,
    float* __restrict__ class_pos,
    float* __restrict__ out) {
  __shared__ float As[32][36];  // +4 pad: float4-aligned, conflict-light
  __shared__ float Bs[32][36];

  const int bi = blockIdx.y, bj = blockIdx.x;
  const int t = threadIdx.x;
  const int lr = t >> 3;         // 0..31 : row to load
  const int lk = (t & 7) << 2;   // 0,4,..,28 : float4 k-offset
  const int ty = t >> 4;         // 0..15
  const int tx = t & 15;         // 0..15

  const float* Ag = pred + (size_t)(bi * 32 + lr) * D + lk;
  const float* Bg = pred + (size_t)(bj * 32 + lr) * D + lk;

  float c00 = 0.f, c01 = 0.f, c10 = 0.f, c11 = 0.f;

  float4 av = *(const float4*)(Ag);
  float4 bv = *(const float4*)(Bg);

  for (int kb = 0; kb < D; kb += 32) {
    *(float4*)(&As[lr][lk]) = av;
    *(float4*)(&Bs[lr][lk]) = bv;
    __syncthreads();
    if (kb + 32 < D) {             // prefetch next staging block
      av = *(const float4*)(Ag + kb + 32);
      bv = *(const float4*)(Bg + kb + 32);
    }
#pragma unroll
    for (int k = 0; k < 32; k += 4) {
      float4 a0 = *(const float4*)(&As[ty][k]);
      float4 a1 = *(const float4*)(&As[ty + 16][k]);
      float4 b0 = *(const float4*)(&Bs[tx][k]);
      float4 b1 = *(const float4*)(&Bs[tx + 16][k]);
      c00 += a0.x * b0.x + a0.y * b0.y + a0.z * b0.z + a0.w * b0.w;
      c01 += a0.x * b1.x + a0.y * b1.y + a0.z * b1.z + a0.w * b1.w;
      c10 += a1.x * b0.x + a1.y * b0.y + a1.z * b0.z + a1.w * b0.w;
      c11 += a1.x * b1.x + a1.y * b1.y + a1.z * b1.z + a1.w * b1.w;
    }
    __syncthreads();
  }

  const int row0 = bi * 32 + ty, row1 = row0 + 16;
  const int col0 = bj * 32 + tx, col1 = col0 + 16;
  G[(size_t)row0 * N + col0] = c00;
  G[(size_t)row0 * N + col1] = c01;
  G[(size_t)row1 * N + col0] = c10;
  G[(size_t)row1 * N + col1] = c11;

  if (bi == bj && tx == ty) {  // c00, c11 are diagonal elements
    inv_n[row0] = 1.0f / fmaxf(sqrtf(c00), EPSF);
    inv_n[row1] = 1.0f / fmaxf(sqrtf(c11), EPSF);
  }
  if (bi == 0 && bj == 0 && t == 0) {
    out[0] = 0.0f;  // d_out is poisoned each launch; k_rows accumulates
    float acc = 0.0f;
    class_pos[0] = 0.0f;
    for (int c = 0; c < NC - 1; c++) {
      acc += log1pf(expf(dist_raw[c]));
      class_pos[c + 1] = acc;
    }
  }
}

// ---------------- Kernel 2: per-row loss + global mean ----------------
__global__ __launch_bounds__(256) void k_rows(
    const float* __restrict__ G,
    const int* __restrict__ target,
    const float* __restrict__ inv_n,
    const float* __restrict__ class_pos,
    float* __restrict__ out) {
  const int i = blockIdx.x;
  const int tid = threadIdx.x;

  __shared__ float s_a[N];   // compacted cos+margin over negatives
  __shared__ float s_p[N];   // compacted cos over positives
  __shared__ float s_cp[NC];
  __shared__ int s_np, s_nn;

  if (tid == 0) { s_np = 0; s_nn = 0; }
  if (tid < NC) s_cp[tid] = class_pos[tid];
  __syncthreads();

  const int ti = target[i];
  const float inv_i = inv_n[i];
  const float cpi = s_cp[ti];

  for (int j = tid; j < N; j += 256) {
    float cosv = G[(size_t)i * N + j] * inv_i * inv_n[j];
    int tj = target[j];
    if (tj != ti) {
      float m = fabsf(cpi - s_cp[tj]);
      int idx = atomicAdd(&s_nn, 1);
      s_a[idx] = cosv + m;
    } else if (j != i) {
      int idx = atomicAdd(&s_np, 1);
      s_p[idx] = cosv;
    }
  }
  __syncthreads();

  const int np = s_np, nn = s_nn;
  // each thread owns a-values at tid and tid+256; loop over positives
  float a0 = (tid < nn) ? s_a[tid] : -1e30f;
  float a1 = (tid + 256 < nn) ? s_a[tid + 256] : -1e30f;
  float acc = 0.0f;
  for (int kk = 0; kk < np; kk++) {
    float ck = s_p[kk];  // LDS broadcast
    acc += fmaxf(a0 - ck, 0.0f) + fmaxf(a1 - ck, 0.0f);
  }

  // block reduce
  for (int off = 32; off > 0; off >>= 1) acc += __shfl_down(acc, off);
  __shared__ float s_part[4];
  if ((tid & 63) == 0) s_part[tid >> 6] = acc;
  __syncthreads();
  if (tid == 0) {
    float total = s_part[0] + s_part[1] + s_part[2] + s_part[3];
    if (np > 0 && nn > 0) {
      float r = total / ((float)nn * (float)nn * (float)np);
      atomicAdd(out, r / (float)N);
    }
  }
}

extern "C" void kernel_launch(void* const* d_in, const int* in_sizes, int n_in,
                              void* d_out, int out_size, void* d_ws, size_t ws_size,
                              hipStream_t stream) {
  const float* pred = (const float*)d_in[0];
  const float* dist_raw = (const float*)d_in[1];
  const int* target = (const int*)d_in[2];
  float* out = (float*)d_out;

  float* G = (float*)d_ws;                   // N*N floats = 1 MB
  float* inv_n = G + (size_t)N * N;          // N floats
  float* class_pos = inv_n + N;              // 16 floats (10 used)

  dim3 ggrid(16, 16);
  k_gram<<<ggrid, 256, 0, stream>>>(pred, dist_raw, G, inv_n, class_pos, out);
  k_rows<<<N, 256, 0, stream>>>(G, target, inv_n, class_pos, out);
}